// Round 6
// baseline (531.134 us; speedup 1.0000x reference)
//
#include <hip/hip_runtime.h>

#define N_NODES 10000
#define N_EDGESN 160000
#define E_TOT   (N_EDGESN + N_NODES)   // 170000
#define C 128
#define H 8
#define G 16
#define LLAYERS 5
#define NUM_FEAT 14
#define DIM_OUT 16
#define CH 16   // C/H
#define CG 8    // C/G
#define XSTRIDE (6*C)        // x_all row stride (6 layer slots)

// ---- counts = 1 (self loop) ----
__global__ void k_zero(int* __restrict__ counts) {
    int i = blockIdx.x * blockDim.x + threadIdx.x;
    if (i < N_NODES) counts[i] = 1;
}

// ---- degree count over original edges (by col) ----
__global__ void k_count(const int* __restrict__ col, int* __restrict__ counts) {
    int e = blockIdx.x * blockDim.x + threadIdx.x;
    if (e < N_EDGESN) atomicAdd(&counts[col[e]], 1);
}

// ---- single-block scan: counts -> exclusive offsets + cursor; dis = rsqrt(counts) ----
__global__ __launch_bounds__(1024) void k_scan(const int* __restrict__ counts,
                                               int* __restrict__ offs, int* __restrict__ cursor,
                                               float* __restrict__ dis) {
    __shared__ int part[1024];
    const int CHK = (N_NODES + 1023) / 1024;   // 10
    int t = threadIdx.x;
    int base = t * CHK;
    int loc[CHK];
    int sum = 0;
#pragma unroll
    for (int i = 0; i < CHK; i++) {
        int idx = base + i;
        int v = (idx < N_NODES) ? counts[idx] : 0;
        loc[i] = sum;
        sum += v;
    }
    part[t] = sum;
    __syncthreads();
    for (int off = 1; off < 1024; off <<= 1) {
        int v = (t >= off) ? part[t - off] : 0;
        __syncthreads();
        part[t] += v;
        __syncthreads();
    }
    int prev = (t > 0) ? part[t - 1] : 0;
#pragma unroll
    for (int i = 0; i < CHK; i++) {
        int idx = base + i;
        if (idx < N_NODES) {
            int o = prev + loc[i];
            offs[idx] = o;
            cursor[idx] = o;
            dis[idx] = rsqrtf((float)counts[idx]);
        }
    }
    if (t == 1023) offs[N_NODES] = part[1023];
}

// ---- scatter edges into dest-sorted CSR; payload = {src, dis[src]} ----
__global__ void k_scatter(const int* __restrict__ row, const int* __restrict__ col,
                          const float* __restrict__ dis,
                          int* __restrict__ cursor, int2* __restrict__ csr) {
    int e = blockIdx.x * blockDim.x + threadIdx.x;
    if (e >= E_TOT) return;
    int r = (e < N_EDGESN) ? row[e] : (e - N_EDGESN);
    int c = (e < N_EDGESN) ? col[e] : (e - N_EDGESN);
    int pos = atomicAdd(&cursor[c], 1);
    int2 pay;
    pay.x = r;
    pay.y = __float_as_int(dis[r]);
    csr[pos] = pay;
}

// ---- lin1: x (n,14) @ w (14,128) + b, relu -> x_all[:,0,:] ----
__global__ __launch_bounds__(256) void k_lin1(const float* __restrict__ x,
                                              const float* __restrict__ w,
                                              const float* __restrict__ b,
                                              float* __restrict__ x_all) {
    __shared__ float sw[NUM_FEAT * C];
    __shared__ float sb[C];
    int tid = threadIdx.x;
    for (int i = tid; i < NUM_FEAT * C; i += 256) sw[i] = w[i];
    if (tid < C) sb[tid] = b[tid];
    __syncthreads();
    int node = blockIdx.x * 2 + tid / C;
    int c = tid & (C - 1);
    if (node >= N_NODES) return;
    const float* xr = x + node * NUM_FEAT;
    float acc = sb[c];
#pragma unroll
    for (int f = 0; f < NUM_FEAT; f++) acc += xr[f] * sw[f * C + c];
    x_all[node * XSTRIDE + c] = fmaxf(acc, 0.0f);
}

__device__ __forceinline__ float dot8(const float4& a, const float4& b, const float (&w)[8]) {
    return a.x * w[0] + a.y * w[1] + a.z * w[2] + a.w * w[3]
         + b.x * w[4] + b.y * w[5] + b.z * w[6] + b.w * w[7];
}
__device__ __forceinline__ float dot8v(const float4& a, const float4& b,
                                       const float4& wa, const float4& wb) {
    return a.x * wa.x + a.y * wa.y + a.z * wa.z + a.w * wa.w
         + b.x * wb.x + b.y * wb.y + b.z * wb.z + b.w * wb.w;
}

// ---- fused attention layer: one block (4 waves) per destination node ----
// Lane owns output channels c0=2*lane,c0+1; its group's 8 input channels are
// loaded directly as 2x float4 (L1-broadcast within the 4-lane group).
// Score uses the precomputed-y trick:
//   score_g = (Wq x_d + bq)_g . (Wk x_s + bk)_g = y_g . x_s[g] + z_g,
//   with y_g = Wk_g^T q_g, z_g = q_g . bk_g  (computed once per node).
// Head score = group partial + shfl_xor(partial, 4)  -> ONE shuffle per slot.
template <int NL>
__global__ __launch_bounds__(256) void k_attn_fly(const int* __restrict__ offs,
                                                  const int2* __restrict__ csr,
                                                  const float* __restrict__ dis,
                                                  const float* __restrict__ Wq, const float* __restrict__ bq,
                                                  const float* __restrict__ Wk, const float* __restrict__ bk,
                                                  const float* __restrict__ Wv, const float* __restrict__ bv,
                                                  float* __restrict__ x_all) {
    const int l = NL - 1;
    __shared__ float red[4][C];
    int d = blockIdx.x;
    int w = threadIdx.x >> 6;
    int lane = threadIdx.x & 63;
    int g = lane >> 2;       // channel group 0..15
    int j4 = lane & 3;
    int o0 = 2 * j4;         // output col within group
    int c0 = 2 * lane;       // absolute channel

    // per-lane V weights (2 output cols of group g)
    const float* Wv_g = Wv + l * (G * CG * CG) + g * (CG * CG);
    float wvA[8], wvB[8];
#pragma unroll
    for (int i = 0; i < 8; i++) {
        wvA[i] = Wv_g[i * CG + o0];
        wvB[i] = Wv_g[i * CG + o0 + 1];
    }
    const float bv0 = bv[l * C + c0], bv1 = bv[l * C + c0 + 1];

    // ---- per-node precompute: q8 -> y8, z ----
    const float* xq = x_all + (size_t)d * XSTRIDE + l * C + 8 * g;
    float4 xda = *(const float4*)xq;
    float4 xdb = *(const float4*)(xq + 4);
    const float* bqg = bq + l * C + 8 * g;
    float4 qa = *(const float4*)bqg;
    float4 qb = *(const float4*)(bqg + 4);
    {
        const float* wq = Wq + l * (G * CG * CG) + g * (CG * CG);
        float xdv[8] = {xda.x, xda.y, xda.z, xda.w, xdb.x, xdb.y, xdb.z, xdb.w};
#pragma unroll
        for (int i = 0; i < 8; i++) {
            float4 ra = *(const float4*)(wq + i * CG);
            float4 rb = *(const float4*)(wq + i * CG + 4);
            qa.x += xdv[i] * ra.x; qa.y += xdv[i] * ra.y;
            qa.z += xdv[i] * ra.z; qa.w += xdv[i] * ra.w;
            qb.x += xdv[i] * rb.x; qb.y += xdv[i] * rb.y;
            qb.z += xdv[i] * rb.z; qb.w += xdv[i] * rb.w;
        }
    }
    float y8[8];
    {
        const float* wk = Wk + l * (G * CG * CG) + g * (CG * CG);
#pragma unroll
        for (int j = 0; j < 8; j++) {
            float4 ra = *(const float4*)(wk + j * CG);
            float4 rb = *(const float4*)(wk + j * CG + 4);
            y8[j] = dot8v(qa, qb, ra, rb);
        }
    }
    const float* bkg = bk + l * C + 8 * g;
    float z = dot8v(qa, qb, *(const float4*)bkg, *(const float4*)(bkg + 4));

    const float disd = dis[d];
    const int p0 = offs[d], p1 = offs[d + 1];
    float ox = 0.0f, oy = 0.0f;
    const float scale = 0.25f;   // 1/sqrt(CH=16)
    for (int p = p0 + w; p < p1; p += 4) {
        int2 pay = csr[p];
        float nrm = disd * __int_as_float(pay.y);
        const float* xs = x_all + (size_t)pay.x * XSTRIDE + 8 * g;
        float sc[NL], vx[NL], vy[NL];
#pragma unroll
        for (int t = 0; t < NL; t++) {
            float4 xa = *(const float4*)(xs + t * C);
            float4 xb = *(const float4*)(xs + t * C + 4);
            float part = z + dot8(xa, xb, y8);
            part += __shfl_xor(part, 4);       // combine the head's two groups
            sc[t] = part * scale;
            vx[t] = bv0 + dot8(xa, xb, wvA);
            vy[t] = bv1 + dot8(xa, xb, wvB);
        }
        float mx = sc[0];
#pragma unroll
        for (int t = 1; t < NL; t++) mx = fmaxf(mx, sc[t]);
        float sum = 0.0f;
#pragma unroll
        for (int t = 0; t < NL; t++) { sc[t] = __expf(sc[t] - mx); sum += sc[t]; }
        float inv = nrm * __builtin_amdgcn_rcpf(sum);
        float ax = 0.0f, ay = 0.0f;
#pragma unroll
        for (int t = 0; t < NL; t++) { ax += sc[t] * vx[t]; ay += sc[t] * vy[t]; }
        ox += ax * inv;
        oy += ay * inv;
    }
    red[w][c0] = ox;
    red[w][c0 + 1] = oy;
    __syncthreads();
    if (threadIdx.x < C) {
        int c = threadIdx.x;
        float v = red[0][c] + red[1][c] + red[2][c] + red[3][c];
        x_all[(size_t)d * XSTRIDE + (l + 1) * C + c] = fmaxf(v, 0.0f);
    }
}

// ---- lin2: x_all[:,5,:] (n,128) @ w (128,16) + b -> out ----
__global__ __launch_bounds__(256) void k_lin2(const float* __restrict__ x_all,
                                              const float* __restrict__ w,
                                              const float* __restrict__ b,
                                              float* __restrict__ out) {
    __shared__ float sw[C * DIM_OUT];
    __shared__ float sb[DIM_OUT];
    __shared__ float sx[16][C];
    int tid = threadIdx.x;
    for (int i = tid; i < C * DIM_OUT; i += 256) sw[i] = w[i];
    if (tid < DIM_OUT) sb[tid] = b[tid];
    int node0 = blockIdx.x * 16;
    for (int i = tid; i < 16 * C; i += 256) {
        int nn = node0 + i / C;
        sx[i / C][i & (C - 1)] = (nn < N_NODES) ? x_all[(size_t)nn * XSTRIDE + 5 * C + (i & (C - 1))] : 0.0f;
    }
    __syncthreads();
    int node = node0 + tid / DIM_OUT;
    int o = tid & (DIM_OUT - 1);
    if (node >= N_NODES) return;
    float acc = sb[o];
    const float* xr = sx[tid / DIM_OUT];
#pragma unroll 8
    for (int c = 0; c < C; c++) acc += xr[c] * sw[c * DIM_OUT + o];
    out[node * DIM_OUT + o] = acc;
}

extern "C" void kernel_launch(void* const* d_in, const int* in_sizes, int n_in,
                              void* d_out, int out_size, void* d_ws, size_t ws_size,
                              hipStream_t stream) {
    const float* x      = (const float*)d_in[0];
    const int*   edge   = (const int*)d_in[1];
    const int*   row    = edge;              // edge_index[0]
    const int*   col    = edge + N_EDGESN;   // edge_index[1]
    const float* lin1_w = (const float*)d_in[2];
    const float* lin1_b = (const float*)d_in[3];
    const float* Wq     = (const float*)d_in[4];
    const float* bq     = (const float*)d_in[5];
    const float* Wk     = (const float*)d_in[6];
    const float* bk     = (const float*)d_in[7];
    const float* Wv     = (const float*)d_in[8];
    const float* bv     = (const float*)d_in[9];
    const float* lin2_w = (const float*)d_in[10];
    const float* lin2_b = (const float*)d_in[11];
    float* outp = (float*)d_out;

    float* ws    = (float*)d_ws;
    float* x_all = ws;                                      // n*6*C
    float* dis   = x_all + (size_t)N_NODES * XSTRIDE;       // n
    int*   counts = (int*)(dis + N_NODES);                  // n
    int*   offs   = counts + N_NODES;                       // n+1
    int*   cursor = offs + N_NODES + 1;                     // n
    int2*  csr    = (int2*)(cursor + N_NODES);              // E_TOT int2

    k_zero<<<(N_NODES + 255) / 256, 256, 0, stream>>>(counts);
    k_count<<<(N_EDGESN + 255) / 256, 256, 0, stream>>>(col, counts);
    k_scan<<<1, 1024, 0, stream>>>(counts, offs, cursor, dis);
    k_scatter<<<(E_TOT + 255) / 256, 256, 0, stream>>>(row, col, dis, cursor, csr);
    k_lin1<<<N_NODES / 2, 256, 0, stream>>>(x, lin1_w, lin1_b, x_all);

    for (int l = 0; l < LLAYERS; l++) {
        switch (l) {
            case 0: k_attn_fly<1><<<N_NODES, 256, 0, stream>>>(offs, csr, dis, Wq, bq, Wk, bk, Wv, bv, x_all); break;
            case 1: k_attn_fly<2><<<N_NODES, 256, 0, stream>>>(offs, csr, dis, Wq, bq, Wk, bk, Wv, bv, x_all); break;
            case 2: k_attn_fly<3><<<N_NODES, 256, 0, stream>>>(offs, csr, dis, Wq, bq, Wk, bk, Wv, bv, x_all); break;
            case 3: k_attn_fly<4><<<N_NODES, 256, 0, stream>>>(offs, csr, dis, Wq, bq, Wk, bk, Wv, bv, x_all); break;
            case 4: k_attn_fly<5><<<N_NODES, 256, 0, stream>>>(offs, csr, dis, Wq, bq, Wk, bk, Wv, bv, x_all); break;
        }
    }
    k_lin2<<<(N_NODES + 15) / 16, 256, 0, stream>>>(x_all, lin2_w, lin2_b, outp);
}

// Round 7
// 496.788 us; speedup vs baseline: 1.0691x; 1.0691x over previous
//
#include <hip/hip_runtime.h>

#define N_NODES 10000
#define N_EDGESN 160000
#define E_TOT   (N_EDGESN + N_NODES)   // 170000
#define C 128
#define H 8
#define G 16
#define LLAYERS 5
#define NUM_FEAT 14
#define DIM_OUT 16
#define CH 16   // C/H
#define CG 8    // C/G
#define XSTRIDE (6*C)        // x_all row stride (6 layer slots)

// ---- counts = 1 (self loop) ----
__global__ void k_zero(int* __restrict__ counts) {
    int i = blockIdx.x * blockDim.x + threadIdx.x;
    if (i < N_NODES) counts[i] = 1;
}

// ---- degree count over original edges (by col) ----
__global__ void k_count(const int* __restrict__ col, int* __restrict__ counts) {
    int e = blockIdx.x * blockDim.x + threadIdx.x;
    if (e < N_EDGESN) atomicAdd(&counts[col[e]], 1);
}

// ---- single-block scan: counts -> exclusive offsets + cursor; dis = rsqrt(counts) ----
__global__ __launch_bounds__(1024) void k_scan(const int* __restrict__ counts,
                                               int* __restrict__ offs, int* __restrict__ cursor,
                                               float* __restrict__ dis) {
    __shared__ int part[1024];
    const int CHK = (N_NODES + 1023) / 1024;   // 10
    int t = threadIdx.x;
    int base = t * CHK;
    int loc[CHK];
    int sum = 0;
#pragma unroll
    for (int i = 0; i < CHK; i++) {
        int idx = base + i;
        int v = (idx < N_NODES) ? counts[idx] : 0;
        loc[i] = sum;
        sum += v;
    }
    part[t] = sum;
    __syncthreads();
    for (int off = 1; off < 1024; off <<= 1) {
        int v = (t >= off) ? part[t - off] : 0;
        __syncthreads();
        part[t] += v;
        __syncthreads();
    }
    int prev = (t > 0) ? part[t - 1] : 0;
#pragma unroll
    for (int i = 0; i < CHK; i++) {
        int idx = base + i;
        if (idx < N_NODES) {
            int o = prev + loc[i];
            offs[idx] = o;
            cursor[idx] = o;
            dis[idx] = rsqrtf((float)counts[idx]);
        }
    }
    if (t == 1023) offs[N_NODES] = part[1023];
}

// ---- scatter edges into dest-sorted CSR; payload = {src, dis[src]} ----
__global__ void k_scatter(const int* __restrict__ row, const int* __restrict__ col,
                          const float* __restrict__ dis,
                          int* __restrict__ cursor, int2* __restrict__ csr) {
    int e = blockIdx.x * blockDim.x + threadIdx.x;
    if (e >= E_TOT) return;
    int r = (e < N_EDGESN) ? row[e] : (e - N_EDGESN);
    int c = (e < N_EDGESN) ? col[e] : (e - N_EDGESN);
    int pos = atomicAdd(&cursor[c], 1);
    int2 pay;
    pay.x = r;
    pay.y = __float_as_int(dis[r]);
    csr[pos] = pay;
}

// ---- lin1: x (n,14) @ w (14,128) + b, relu -> x_all[:,0,:] ----
__global__ __launch_bounds__(256) void k_lin1(const float* __restrict__ x,
                                              const float* __restrict__ w,
                                              const float* __restrict__ b,
                                              float* __restrict__ x_all) {
    __shared__ float sw[NUM_FEAT * C];
    __shared__ float sb[C];
    int tid = threadIdx.x;
    for (int i = tid; i < NUM_FEAT * C; i += 256) sw[i] = w[i];
    if (tid < C) sb[tid] = b[tid];
    __syncthreads();
    int node = blockIdx.x * 2 + tid / C;
    int c = tid & (C - 1);
    if (node >= N_NODES) return;
    const float* xr = x + node * NUM_FEAT;
    float acc = sb[c];
#pragma unroll
    for (int f = 0; f < NUM_FEAT; f++) acc += xr[f] * sw[f * C + c];
    x_all[node * XSTRIDE + c] = fmaxf(acc, 0.0f);
}

__device__ __forceinline__ float dot8(const float4& a, const float4& b, const float (&w)[8]) {
    return a.x * w[0] + a.y * w[1] + a.z * w[2] + a.w * w[3]
         + b.x * w[4] + b.y * w[5] + b.z * w[6] + b.w * w[7];
}
__device__ __forceinline__ float dot8v(const float4& a, const float4& b,
                                       const float4& wa, const float4& wb) {
    return a.x * wa.x + a.y * wa.y + a.z * wa.z + a.w * wa.w
         + b.x * wb.x + b.y * wb.y + b.z * wb.z + b.w * wb.w;
}

// ---- fused attention layer with V-fold ----
// One block (4 waves) per destination node; lane serves channel-group g=lane>>2.
// Per edge-slot only the SCORE is computed (y_d.x_s + z, one shfl);
// x itself is accumulated with weights alpha (xacc8). The V transform
// (out = Wv xacc + bv*nsum, relu) runs once per node in the epilogue:
//   agg_d = sum_e n_e sum_t a_et (Wv x_t + bv) = Wv (sum n a x) + bv (sum n).
template <int NL>
__global__ __launch_bounds__(256) void k_attn_fly(const int* __restrict__ offs,
                                                  const int2* __restrict__ csr,
                                                  const float* __restrict__ dis,
                                                  const float* __restrict__ Wq, const float* __restrict__ bq,
                                                  const float* __restrict__ Wk, const float* __restrict__ bk,
                                                  const float* __restrict__ Wv, const float* __restrict__ bv,
                                                  float* __restrict__ x_all) {
    const int l = NL - 1;
    __shared__ float red[4][C];
    __shared__ float redn[4];
    int d = blockIdx.x;
    int w = threadIdx.x >> 6;
    int lane = threadIdx.x & 63;
    int g = lane >> 2;       // channel group 0..15

    // ---- per-node precompute: q8 -> y8, z ----
    const float* xq = x_all + (size_t)d * XSTRIDE + l * C + 8 * g;
    float4 xda = *(const float4*)xq;
    float4 xdb = *(const float4*)(xq + 4);
    const float* bqg = bq + l * C + 8 * g;
    float4 qa = *(const float4*)bqg;
    float4 qb = *(const float4*)(bqg + 4);
    {
        const float* wq = Wq + l * (G * CG * CG) + g * (CG * CG);
        float xdv[8] = {xda.x, xda.y, xda.z, xda.w, xdb.x, xdb.y, xdb.z, xdb.w};
#pragma unroll
        for (int i = 0; i < 8; i++) {
            float4 ra = *(const float4*)(wq + i * CG);
            float4 rb = *(const float4*)(wq + i * CG + 4);
            qa.x += xdv[i] * ra.x; qa.y += xdv[i] * ra.y;
            qa.z += xdv[i] * ra.z; qa.w += xdv[i] * ra.w;
            qb.x += xdv[i] * rb.x; qb.y += xdv[i] * rb.y;
            qb.z += xdv[i] * rb.z; qb.w += xdv[i] * rb.w;
        }
    }
    float y8[8];
    {
        const float* wk = Wk + l * (G * CG * CG) + g * (CG * CG);
#pragma unroll
        for (int j = 0; j < 8; j++) {
            float4 ra = *(const float4*)(wk + j * CG);
            float4 rb = *(const float4*)(wk + j * CG + 4);
            y8[j] = dot8v(qa, qb, ra, rb);
        }
    }
    const float* bkg = bk + l * C + 8 * g;
    float z = dot8v(qa, qb, *(const float4*)bkg, *(const float4*)(bkg + 4));

    const float disd = dis[d];
    const int p0 = offs[d], p1 = offs[d + 1];
    const float scale = 0.25f;   // 1/sqrt(CH=16)
    float xacc[8] = {0.f, 0.f, 0.f, 0.f, 0.f, 0.f, 0.f, 0.f};
    float nsum = 0.f;

    int p = p0 + w;
    int2 pay = (p < p1) ? csr[p] : make_int2(0, 0);
    for (; p < p1; p += 4) {
        int2 nxt = (p + 4 < p1) ? csr[p + 4] : make_int2(0, 0);   // prefetch
        float nrm = disd * __int_as_float(pay.y);
        const float* xs = x_all + (size_t)pay.x * XSTRIDE + 8 * g;
        float4 xa[NL], xb[NL];
        float sc[NL];
#pragma unroll
        for (int t = 0; t < NL; t++) {
            xa[t] = *(const float4*)(xs + t * C);
            xb[t] = *(const float4*)(xs + t * C + 4);
            float part = z + dot8(xa[t], xb[t], y8);
            part += __shfl_xor(part, 4);       // combine the head's two groups
            sc[t] = part * scale;
        }
        float mx = sc[0];
#pragma unroll
        for (int t = 1; t < NL; t++) mx = fmaxf(mx, sc[t]);
        float s = 0.f;
        float ex[8] = {0.f, 0.f, 0.f, 0.f, 0.f, 0.f, 0.f, 0.f};
#pragma unroll
        for (int t = 0; t < NL; t++) {
            float e = __expf(sc[t] - mx);
            s += e;
            ex[0] += e * xa[t].x; ex[1] += e * xa[t].y;
            ex[2] += e * xa[t].z; ex[3] += e * xa[t].w;
            ex[4] += e * xb[t].x; ex[5] += e * xb[t].y;
            ex[6] += e * xb[t].z; ex[7] += e * xb[t].w;
        }
        float inv = nrm * __builtin_amdgcn_rcpf(s);
#pragma unroll
        for (int i = 0; i < 8; i++) xacc[i] += inv * ex[i];
        nsum += nrm;
        pay = nxt;
    }

    // per-wave partials: group channels [8g,8g+8) (4 lanes of a group identical)
    if ((lane & 3) == 0) {
#pragma unroll
        for (int i = 0; i < 8; i++) red[w][8 * g + i] = xacc[i];
    }
    if (lane == 0) redn[w] = nsum;
    __syncthreads();
    if (threadIdx.x < C) {
        int c = threadIdx.x;
        red[0][c] = red[0][c] + red[1][c] + red[2][c] + red[3][c];
    }
    __syncthreads();
    if (threadIdx.x < C) {
        int c = threadIdx.x;
        int gg = c >> 3, oo = c & 7;
        float ns = redn[0] + redn[1] + redn[2] + redn[3];
        const float* wv = Wv + l * (G * CG * CG) + gg * (CG * CG);
        float acc = bv[l * C + c] * ns;
#pragma unroll
        for (int i = 0; i < 8; i++) acc += red[0][8 * gg + i] * wv[i * CG + oo];
        x_all[(size_t)d * XSTRIDE + (l + 1) * C + c] = fmaxf(acc, 0.f);
    }
}

// ---- lin2: x_all[:,5,:] (n,128) @ w (128,16) + b -> out ----
__global__ __launch_bounds__(256) void k_lin2(const float* __restrict__ x_all,
                                              const float* __restrict__ w,
                                              const float* __restrict__ b,
                                              float* __restrict__ out) {
    __shared__ float sw[C * DIM_OUT];
    __shared__ float sb[DIM_OUT];
    __shared__ float sx[16][C];
    int tid = threadIdx.x;
    for (int i = tid; i < C * DIM_OUT; i += 256) sw[i] = w[i];
    if (tid < DIM_OUT) sb[tid] = b[tid];
    int node0 = blockIdx.x * 16;
    for (int i = tid; i < 16 * C; i += 256) {
        int nn = node0 + i / C;
        sx[i / C][i & (C - 1)] = (nn < N_NODES) ? x_all[(size_t)nn * XSTRIDE + 5 * C + (i & (C - 1))] : 0.0f;
    }
    __syncthreads();
    int node = node0 + tid / DIM_OUT;
    int o = tid & (DIM_OUT - 1);
    if (node >= N_NODES) return;
    float acc = sb[o];
    const float* xr = sx[tid / DIM_OUT];
#pragma unroll 8
    for (int c = 0; c < C; c++) acc += xr[c] * sw[c * DIM_OUT + o];
    out[node * DIM_OUT + o] = acc;
}

extern "C" void kernel_launch(void* const* d_in, const int* in_sizes, int n_in,
                              void* d_out, int out_size, void* d_ws, size_t ws_size,
                              hipStream_t stream) {
    const float* x      = (const float*)d_in[0];
    const int*   edge   = (const int*)d_in[1];
    const int*   row    = edge;              // edge_index[0]
    const int*   col    = edge + N_EDGESN;   // edge_index[1]
    const float* lin1_w = (const float*)d_in[2];
    const float* lin1_b = (const float*)d_in[3];
    const float* Wq     = (const float*)d_in[4];
    const float* bq     = (const float*)d_in[5];
    const float* Wk     = (const float*)d_in[6];
    const float* bk     = (const float*)d_in[7];
    const float* Wv     = (const float*)d_in[8];
    const float* bv     = (const float*)d_in[9];
    const float* lin2_w = (const float*)d_in[10];
    const float* lin2_b = (const float*)d_in[11];
    float* outp = (float*)d_out;

    float* ws    = (float*)d_ws;
    float* x_all = ws;                                      // n*6*C
    float* dis   = x_all + (size_t)N_NODES * XSTRIDE;       // n
    int*   counts = (int*)(dis + N_NODES);                  // n
    int*   offs   = counts + N_NODES;                       // n+1
    int*   cursor = offs + N_NODES + 1;                     // n
    int2*  csr    = (int2*)(cursor + N_NODES);              // E_TOT int2

    k_zero<<<(N_NODES + 255) / 256, 256, 0, stream>>>(counts);
    k_count<<<(N_EDGESN + 255) / 256, 256, 0, stream>>>(col, counts);
    k_scan<<<1, 1024, 0, stream>>>(counts, offs, cursor, dis);
    k_scatter<<<(E_TOT + 255) / 256, 256, 0, stream>>>(row, col, dis, cursor, csr);
    k_lin1<<<N_NODES / 2, 256, 0, stream>>>(x, lin1_w, lin1_b, x_all);

    for (int l = 0; l < LLAYERS; l++) {
        switch (l) {
            case 0: k_attn_fly<1><<<N_NODES, 256, 0, stream>>>(offs, csr, dis, Wq, bq, Wk, bk, Wv, bv, x_all); break;
            case 1: k_attn_fly<2><<<N_NODES, 256, 0, stream>>>(offs, csr, dis, Wq, bq, Wk, bk, Wv, bv, x_all); break;
            case 2: k_attn_fly<3><<<N_NODES, 256, 0, stream>>>(offs, csr, dis, Wq, bq, Wk, bk, Wv, bv, x_all); break;
            case 3: k_attn_fly<4><<<N_NODES, 256, 0, stream>>>(offs, csr, dis, Wq, bq, Wk, bk, Wv, bv, x_all); break;
            case 4: k_attn_fly<5><<<N_NODES, 256, 0, stream>>>(offs, csr, dis, Wq, bq, Wk, bk, Wv, bv, x_all); break;
        }
    }
    k_lin2<<<(N_NODES + 15) / 16, 256, 0, stream>>>(x_all, lin2_w, lin2_b, outp);
}

// Round 8
// 450.598 us; speedup vs baseline: 1.1787x; 1.1025x over previous
//
#include <hip/hip_runtime.h>

#define N_NODES 10000
#define N_EDGESN 160000
#define E_TOT   (N_EDGESN + N_NODES)   // 170000
#define C 128
#define H 8
#define G 16
#define LLAYERS 5
#define NUM_FEAT 14
#define DIM_OUT 16
#define CH 16   // C/H
#define CG 8    // C/G
#define XSTRIDE (6*C)        // x_all row stride (6 layer slots)

// ---- counts = 1 (self loop) ----
__global__ void k_zero(int* __restrict__ counts) {
    int i = blockIdx.x * blockDim.x + threadIdx.x;
    if (i < N_NODES) counts[i] = 1;
}

// ---- degree count over original edges (by col) ----
__global__ void k_count(const int* __restrict__ col, int* __restrict__ counts) {
    int e = blockIdx.x * blockDim.x + threadIdx.x;
    if (e < N_EDGESN) atomicAdd(&counts[col[e]], 1);
}

// ---- single-block scan: counts -> exclusive offsets + cursor; dis = rsqrt(counts) ----
__global__ __launch_bounds__(1024) void k_scan(const int* __restrict__ counts,
                                               int* __restrict__ offs, int* __restrict__ cursor,
                                               float* __restrict__ dis) {
    __shared__ int part[1024];
    const int CHK = (N_NODES + 1023) / 1024;   // 10
    int t = threadIdx.x;
    int base = t * CHK;
    int loc[CHK];
    int sum = 0;
#pragma unroll
    for (int i = 0; i < CHK; i++) {
        int idx = base + i;
        int v = (idx < N_NODES) ? counts[idx] : 0;
        loc[i] = sum;
        sum += v;
    }
    part[t] = sum;
    __syncthreads();
    for (int off = 1; off < 1024; off <<= 1) {
        int v = (t >= off) ? part[t - off] : 0;
        __syncthreads();
        part[t] += v;
        __syncthreads();
    }
    int prev = (t > 0) ? part[t - 1] : 0;
#pragma unroll
    for (int i = 0; i < CHK; i++) {
        int idx = base + i;
        if (idx < N_NODES) {
            int o = prev + loc[i];
            offs[idx] = o;
            cursor[idx] = o;
            dis[idx] = rsqrtf((float)counts[idx]);
        }
    }
    if (t == 1023) offs[N_NODES] = part[1023];
}

// ---- scatter edges into dest-sorted CSR; payload = {src, dis[src]} ----
__global__ void k_scatter(const int* __restrict__ row, const int* __restrict__ col,
                          const float* __restrict__ dis,
                          int* __restrict__ cursor, int2* __restrict__ csr) {
    int e = blockIdx.x * blockDim.x + threadIdx.x;
    if (e >= E_TOT) return;
    int r = (e < N_EDGESN) ? row[e] : (e - N_EDGESN);
    int c = (e < N_EDGESN) ? col[e] : (e - N_EDGESN);
    int pos = atomicAdd(&cursor[c], 1);
    int2 pay;
    pay.x = r;
    pay.y = __float_as_int(dis[r]);
    csr[pos] = pay;
}

// ---- lin1: x (n,14) @ w (14,128) + b, relu -> x_all[:,0,:] ----
__global__ __launch_bounds__(256) void k_lin1(const float* __restrict__ x,
                                              const float* __restrict__ w,
                                              const float* __restrict__ b,
                                              float* __restrict__ x_all) {
    __shared__ float sw[NUM_FEAT * C];
    __shared__ float sb[C];
    int tid = threadIdx.x;
    for (int i = tid; i < NUM_FEAT * C; i += 256) sw[i] = w[i];
    if (tid < C) sb[tid] = b[tid];
    __syncthreads();
    int node = blockIdx.x * 2 + tid / C;
    int c = tid & (C - 1);
    if (node >= N_NODES) return;
    const float* xr = x + node * NUM_FEAT;
    float acc = sb[c];
#pragma unroll
    for (int f = 0; f < NUM_FEAT; f++) acc += xr[f] * sw[f * C + c];
    x_all[node * XSTRIDE + c] = fmaxf(acc, 0.0f);
}

__device__ __forceinline__ float dot8(const float4& a, const float4& b, const float (&w)[8]) {
    return a.x * w[0] + a.y * w[1] + a.z * w[2] + a.w * w[3]
         + b.x * w[4] + b.y * w[5] + b.z * w[6] + b.w * w[7];
}
__device__ __forceinline__ float dot8v(const float4& a, const float4& b,
                                       const float4& wa, const float4& wb) {
    return a.x * wa.x + a.y * wa.y + a.z * wa.z + a.w * wa.w
         + b.x * wb.x + b.y * wb.y + b.z * wb.z + b.w * wb.w;
}

// ---- fused attention layer with V-fold + lane-level edge parallelism ----
// One block (4 waves) per destination node. Lane = (group g, slice j4).
// Each j4-slice of a wave processes a DIFFERENT edge (p = p0+4w+j4, stride 16)
// -> 16 edges in flight per block iteration, no redundant lanes.
// Score: y_d.x_s + z per group; head = part + shfl_xor(part,4) (same j4).
// xacc/nsum folded across j4 by shfl_xor(1),shfl_xor(2) after the loop.
// Epilogue applies Wv once per node: agg = Wv (sum n a x) + bv (sum n), relu.
template <int NL>
__global__ __launch_bounds__(256) void k_attn_fly(const int* __restrict__ offs,
                                                  const int2* __restrict__ csr,
                                                  const float* __restrict__ dis,
                                                  const float* __restrict__ Wq, const float* __restrict__ bq,
                                                  const float* __restrict__ Wk, const float* __restrict__ bk,
                                                  const float* __restrict__ Wv, const float* __restrict__ bv,
                                                  float* __restrict__ x_all) {
    const int l = NL - 1;
    __shared__ float red[4][C];
    __shared__ float redn[4];
    int d = blockIdx.x;
    int w = threadIdx.x >> 6;
    int lane = threadIdx.x & 63;
    int g = lane >> 2;       // channel group 0..15
    int j4 = lane & 3;       // edge slice within wave

    // ---- per-node precompute: q8 -> y8, z ----
    const float* xq = x_all + (size_t)d * XSTRIDE + l * C + 8 * g;
    float4 xda = *(const float4*)xq;
    float4 xdb = *(const float4*)(xq + 4);
    const float* bqg = bq + l * C + 8 * g;
    float4 qa = *(const float4*)bqg;
    float4 qb = *(const float4*)(bqg + 4);
    {
        const float* wq = Wq + l * (G * CG * CG) + g * (CG * CG);
        float xdv[8] = {xda.x, xda.y, xda.z, xda.w, xdb.x, xdb.y, xdb.z, xdb.w};
#pragma unroll
        for (int i = 0; i < 8; i++) {
            float4 ra = *(const float4*)(wq + i * CG);
            float4 rb = *(const float4*)(wq + i * CG + 4);
            qa.x += xdv[i] * ra.x; qa.y += xdv[i] * ra.y;
            qa.z += xdv[i] * ra.z; qa.w += xdv[i] * ra.w;
            qb.x += xdv[i] * rb.x; qb.y += xdv[i] * rb.y;
            qb.z += xdv[i] * rb.z; qb.w += xdv[i] * rb.w;
        }
    }
    float y8[8];
    {
        const float* wk = Wk + l * (G * CG * CG) + g * (CG * CG);
#pragma unroll
        for (int j = 0; j < 8; j++) {
            float4 ra = *(const float4*)(wk + j * CG);
            float4 rb = *(const float4*)(wk + j * CG + 4);
            y8[j] = dot8v(qa, qb, ra, rb);
        }
    }
    const float* bkg = bk + l * C + 8 * g;
    float z = dot8v(qa, qb, *(const float4*)bkg, *(const float4*)(bkg + 4));

    const float disd = dis[d];
    const int p0 = offs[d], p1 = offs[d + 1];
    const float scale = 0.25f;   // 1/sqrt(CH=16)
    float xacc[8] = {0.f, 0.f, 0.f, 0.f, 0.f, 0.f, 0.f, 0.f};
    float nsum = 0.f;

    for (int p = p0 + 4 * w + j4; p < p1; p += 16) {
        int2 pay = csr[p];
        float nrm = disd * __int_as_float(pay.y);
        const float* xs = x_all + (size_t)pay.x * XSTRIDE + 8 * g;
        float4 xa[NL], xb[NL];
        float sc[NL];
#pragma unroll
        for (int t = 0; t < NL; t++) {
            xa[t] = *(const float4*)(xs + t * C);
            xb[t] = *(const float4*)(xs + t * C + 4);
            float part = z + dot8(xa[t], xb[t], y8);
            part += __shfl_xor(part, 4);       // combine the head's two groups (same j4)
            sc[t] = part * scale;
        }
        float mx = sc[0];
#pragma unroll
        for (int t = 1; t < NL; t++) mx = fmaxf(mx, sc[t]);
        float s = 0.f;
        float ex[8] = {0.f, 0.f, 0.f, 0.f, 0.f, 0.f, 0.f, 0.f};
#pragma unroll
        for (int t = 0; t < NL; t++) {
            float e = __expf(sc[t] - mx);
            s += e;
            ex[0] += e * xa[t].x; ex[1] += e * xa[t].y;
            ex[2] += e * xa[t].z; ex[3] += e * xa[t].w;
            ex[4] += e * xb[t].x; ex[5] += e * xb[t].y;
            ex[6] += e * xb[t].z; ex[7] += e * xb[t].w;
        }
        float inv = nrm * __builtin_amdgcn_rcpf(s);
#pragma unroll
        for (int i = 0; i < 8; i++) xacc[i] += inv * ex[i];
        nsum += nrm;
    }

    // fold the 4 j4-slices of each group (lane bits 0,1)
#pragma unroll
    for (int i = 0; i < 8; i++) {
        xacc[i] += __shfl_xor(xacc[i], 1);
        xacc[i] += __shfl_xor(xacc[i], 2);
    }
    nsum += __shfl_xor(nsum, 1);
    nsum += __shfl_xor(nsum, 2);

    if (j4 == 0) {
#pragma unroll
        for (int i = 0; i < 8; i++) red[w][8 * g + i] = xacc[i];
    }
    if (lane == 0) redn[w] = nsum;
    __syncthreads();
    if (threadIdx.x < C) {
        int c = threadIdx.x;
        red[0][c] = red[0][c] + red[1][c] + red[2][c] + red[3][c];
    }
    __syncthreads();
    if (threadIdx.x < C) {
        int c = threadIdx.x;
        int gg = c >> 3, oo = c & 7;
        float ns = redn[0] + redn[1] + redn[2] + redn[3];
        const float* wv = Wv + l * (G * CG * CG) + gg * (CG * CG);
        float acc = bv[l * C + c] * ns;
#pragma unroll
        for (int i = 0; i < 8; i++) acc += red[0][8 * gg + i] * wv[i * CG + oo];
        x_all[(size_t)d * XSTRIDE + (l + 1) * C + c] = fmaxf(acc, 0.f);
    }
}

// ---- lin2: x_all[:,5,:] (n,128) @ w (128,16) + b -> out ----
__global__ __launch_bounds__(256) void k_lin2(const float* __restrict__ x_all,
                                              const float* __restrict__ w,
                                              const float* __restrict__ b,
                                              float* __restrict__ out) {
    __shared__ float sw[C * DIM_OUT];
    __shared__ float sb[DIM_OUT];
    __shared__ float sx[16][C];
    int tid = threadIdx.x;
    for (int i = tid; i < C * DIM_OUT; i += 256) sw[i] = w[i];
    if (tid < DIM_OUT) sb[tid] = b[tid];
    int node0 = blockIdx.x * 16;
    for (int i = tid; i < 16 * C; i += 256) {
        int nn = node0 + i / C;
        sx[i / C][i & (C - 1)] = (nn < N_NODES) ? x_all[(size_t)nn * XSTRIDE + 5 * C + (i & (C - 1))] : 0.0f;
    }
    __syncthreads();
    int node = node0 + tid / DIM_OUT;
    int o = tid & (DIM_OUT - 1);
    if (node >= N_NODES) return;
    float acc = sb[o];
    const float* xr = sx[tid / DIM_OUT];
#pragma unroll 8
    for (int c = 0; c < C; c++) acc += xr[c] * sw[c * DIM_OUT + o];
    out[node * DIM_OUT + o] = acc;
}

extern "C" void kernel_launch(void* const* d_in, const int* in_sizes, int n_in,
                              void* d_out, int out_size, void* d_ws, size_t ws_size,
                              hipStream_t stream) {
    const float* x      = (const float*)d_in[0];
    const int*   edge   = (const int*)d_in[1];
    const int*   row    = edge;              // edge_index[0]
    const int*   col    = edge + N_EDGESN;   // edge_index[1]
    const float* lin1_w = (const float*)d_in[2];
    const float* lin1_b = (const float*)d_in[3];
    const float* Wq     = (const float*)d_in[4];
    const float* bq     = (const float*)d_in[5];
    const float* Wk     = (const float*)d_in[6];
    const float* bk     = (const float*)d_in[7];
    const float* Wv     = (const float*)d_in[8];
    const float* bv     = (const float*)d_in[9];
    const float* lin2_w = (const float*)d_in[10];
    const float* lin2_b = (const float*)d_in[11];
    float* outp = (float*)d_out;

    float* ws    = (float*)d_ws;
    float* x_all = ws;                                      // n*6*C
    float* dis   = x_all + (size_t)N_NODES * XSTRIDE;       // n
    int*   counts = (int*)(dis + N_NODES);                  // n
    int*   offs   = counts + N_NODES;                       // n+1
    int*   cursor = offs + N_NODES + 1;                     // n
    int2*  csr    = (int2*)(cursor + N_NODES);              // E_TOT int2

    k_zero<<<(N_NODES + 255) / 256, 256, 0, stream>>>(counts);
    k_count<<<(N_EDGESN + 255) / 256, 256, 0, stream>>>(col, counts);
    k_scan<<<1, 1024, 0, stream>>>(counts, offs, cursor, dis);
    k_scatter<<<(E_TOT + 255) / 256, 256, 0, stream>>>(row, col, dis, cursor, csr);
    k_lin1<<<N_NODES / 2, 256, 0, stream>>>(x, lin1_w, lin1_b, x_all);

    for (int l = 0; l < LLAYERS; l++) {
        switch (l) {
            case 0: k_attn_fly<1><<<N_NODES, 256, 0, stream>>>(offs, csr, dis, Wq, bq, Wk, bk, Wv, bv, x_all); break;
            case 1: k_attn_fly<2><<<N_NODES, 256, 0, stream>>>(offs, csr, dis, Wq, bq, Wk, bk, Wv, bv, x_all); break;
            case 2: k_attn_fly<3><<<N_NODES, 256, 0, stream>>>(offs, csr, dis, Wq, bq, Wk, bk, Wv, bv, x_all); break;
            case 3: k_attn_fly<4><<<N_NODES, 256, 0, stream>>>(offs, csr, dis, Wq, bq, Wk, bk, Wv, bv, x_all); break;
            case 4: k_attn_fly<5><<<N_NODES, 256, 0, stream>>>(offs, csr, dis, Wq, bq, Wk, bk, Wv, bv, x_all); break;
        }
    }
    k_lin2<<<(N_NODES + 15) / 16, 256, 0, stream>>>(x_all, lin2_w, lin2_b, outp);
}

// Round 9
// 239.001 us; speedup vs baseline: 2.2223x; 1.8853x over previous
//
#include <hip/hip_runtime.h>

#define N_NODES 10000
#define N_EDGESN 160000
#define E_TOT   (N_EDGESN + N_NODES)   // 170000
#define C 128
#define H 8
#define G 16
#define LLAYERS 5
#define NUM_FEAT 14
#define DIM_OUT 16
#define CH 16   // C/H
#define CG 8    // C/G
#define XSTRIDE (6*C)        // x_all row stride (6 layer slots), fp32
#define X16STRIDE (6*C)      // x16 row stride, fp16

typedef _Float16 half8 __attribute__((ext_vector_type(8)));
typedef _Float16 half2v __attribute__((ext_vector_type(2)));

// ---- counts = 1 (self loop) ----
__global__ void k_zero(int* __restrict__ counts) {
    int i = blockIdx.x * blockDim.x + threadIdx.x;
    if (i < N_NODES) counts[i] = 1;
}

// ---- degree count over original edges (by col) ----
__global__ void k_count(const int* __restrict__ col, int* __restrict__ counts) {
    int e = blockIdx.x * blockDim.x + threadIdx.x;
    if (e < N_EDGESN) atomicAdd(&counts[col[e]], 1);
}

// ---- single-block scan: counts -> exclusive offsets + cursor; dis = rsqrt(counts) ----
__global__ __launch_bounds__(1024) void k_scan(const int* __restrict__ counts,
                                               int* __restrict__ offs, int* __restrict__ cursor,
                                               float* __restrict__ dis) {
    __shared__ int part[1024];
    const int CHK = (N_NODES + 1023) / 1024;   // 10
    int t = threadIdx.x;
    int base = t * CHK;
    int loc[CHK];
    int sum = 0;
#pragma unroll
    for (int i = 0; i < CHK; i++) {
        int idx = base + i;
        int v = (idx < N_NODES) ? counts[idx] : 0;
        loc[i] = sum;
        sum += v;
    }
    part[t] = sum;
    __syncthreads();
    for (int off = 1; off < 1024; off <<= 1) {
        int v = (t >= off) ? part[t - off] : 0;
        __syncthreads();
        part[t] += v;
        __syncthreads();
    }
    int prev = (t > 0) ? part[t - 1] : 0;
#pragma unroll
    for (int i = 0; i < CHK; i++) {
        int idx = base + i;
        if (idx < N_NODES) {
            int o = prev + loc[i];
            offs[idx] = o;
            cursor[idx] = o;
            dis[idx] = rsqrtf((float)counts[idx]);
        }
    }
    if (t == 1023) offs[N_NODES] = part[1023];
}

// ---- scatter edges into dest-sorted CSR; payload = {src, dis[src]} ----
__global__ void k_scatter(const int* __restrict__ row, const int* __restrict__ col,
                          const float* __restrict__ dis,
                          int* __restrict__ cursor, int2* __restrict__ csr) {
    int e = blockIdx.x * blockDim.x + threadIdx.x;
    if (e >= E_TOT) return;
    int r = (e < N_EDGESN) ? row[e] : (e - N_EDGESN);
    int c = (e < N_EDGESN) ? col[e] : (e - N_EDGESN);
    int pos = atomicAdd(&cursor[c], 1);
    int2 pay;
    pay.x = r;
    pay.y = __float_as_int(dis[r]);
    csr[pos] = pay;
}

// ---- lin1: x (n,14) @ w (14,128) + b, relu -> x_all[:,0,:] (+ fp16 copy) ----
__global__ __launch_bounds__(256) void k_lin1(const float* __restrict__ x,
                                              const float* __restrict__ w,
                                              const float* __restrict__ b,
                                              float* __restrict__ x_all,
                                              _Float16* __restrict__ x16) {
    __shared__ float sw[NUM_FEAT * C];
    __shared__ float sb[C];
    int tid = threadIdx.x;
    for (int i = tid; i < NUM_FEAT * C; i += 256) sw[i] = w[i];
    if (tid < C) sb[tid] = b[tid];
    __syncthreads();
    int node = blockIdx.x * 2 + tid / C;
    int c = tid & (C - 1);
    if (node >= N_NODES) return;
    const float* xr = x + node * NUM_FEAT;
    float acc = sb[c];
#pragma unroll
    for (int f = 0; f < NUM_FEAT; f++) acc += xr[f] * sw[f * C + c];
    acc = fmaxf(acc, 0.0f);
    x_all[node * XSTRIDE + c] = acc;
    x16[(size_t)node * X16STRIDE + c] = (_Float16)acc;
}

__device__ __forceinline__ float dot8v(const float4& a, const float4& b,
                                       const float4& wa, const float4& wb) {
    return a.x * wa.x + a.y * wa.y + a.z * wa.z + a.w * wa.w
         + b.x * wb.x + b.y * wb.y + b.z * wb.z + b.w * wb.w;
}

// ---- fused attention layer: ONE WAVE PER NODE, fp16 gather, V-fold ----
// 4 waves/block, wave w -> node d = blockIdx*4+w. Lane = (group g, slice j4).
// Slice j4 walks edges p = p0+j4 stride 4. Score = y_d.x16_s + z per group,
// head = part + shfl_xor(part,4). NL==1: softmax degenerates to 1 -> no scores.
// xacc/nsum folded over j4 by shfl_xor(1),(2); V applied once in epilogue.
template <int NL>
__global__ __launch_bounds__(256) void k_attn_fly(const int* __restrict__ offs,
                                                  const int2* __restrict__ csr,
                                                  const float* __restrict__ dis,
                                                  const float* __restrict__ Wq, const float* __restrict__ bq,
                                                  const float* __restrict__ Wk, const float* __restrict__ bk,
                                                  const float* __restrict__ Wv, const float* __restrict__ bv,
                                                  float* __restrict__ x_all,
                                                  _Float16* __restrict__ x16) {
    const int l = NL - 1;
    int w = threadIdx.x >> 6;
    int lane = threadIdx.x & 63;
    int d = blockIdx.x * 4 + w;
    if (d >= N_NODES) return;
    int g = lane >> 2;       // channel group 0..15
    int j4 = lane & 3;       // edge slice within wave
    int c0 = 2 * lane;       // output channels c0, c0+1  (= 8g + 2*j4)
    int o0 = 2 * j4;

    float y8[8];
    float z = 0.f;
    if constexpr (NL > 1) {
        // ---- per-node precompute: q8 -> y8, z (fp32 path) ----
        const float* xq = x_all + (size_t)d * XSTRIDE + l * C + 8 * g;
        float4 xda = *(const float4*)xq;
        float4 xdb = *(const float4*)(xq + 4);
        const float* bqg = bq + l * C + 8 * g;
        float4 qa = *(const float4*)bqg;
        float4 qb = *(const float4*)(bqg + 4);
        const float* wq = Wq + l * (G * CG * CG) + g * (CG * CG);
        float xdv[8] = {xda.x, xda.y, xda.z, xda.w, xdb.x, xdb.y, xdb.z, xdb.w};
#pragma unroll
        for (int i = 0; i < 8; i++) {
            float4 ra = *(const float4*)(wq + i * CG);
            float4 rb = *(const float4*)(wq + i * CG + 4);
            qa.x += xdv[i] * ra.x; qa.y += xdv[i] * ra.y;
            qa.z += xdv[i] * ra.z; qa.w += xdv[i] * ra.w;
            qb.x += xdv[i] * rb.x; qb.y += xdv[i] * rb.y;
            qb.z += xdv[i] * rb.z; qb.w += xdv[i] * rb.w;
        }
        const float* wk = Wk + l * (G * CG * CG) + g * (CG * CG);
#pragma unroll
        for (int j = 0; j < 8; j++) {
            float4 ra = *(const float4*)(wk + j * CG);
            float4 rb = *(const float4*)(wk + j * CG + 4);
            y8[j] = dot8v(qa, qb, ra, rb);
        }
        const float* bkg = bk + l * C + 8 * g;
        z = dot8v(qa, qb, *(const float4*)bkg, *(const float4*)(bkg + 4));
    }

    const float disd = dis[d];
    const int p0 = offs[d], p1 = offs[d + 1];
    const float scale = 0.25f;   // 1/sqrt(CH=16)
    float xacc[8] = {0.f, 0.f, 0.f, 0.f, 0.f, 0.f, 0.f, 0.f};
    float nsum = 0.f;

    for (int p = p0 + j4; p < p1; p += 4) {
        int2 pay = csr[p];
        float nrm = disd * __int_as_float(pay.y);
        const _Float16* xs = x16 + (size_t)pay.x * X16STRIDE + 8 * g;
        if constexpr (NL == 1) {
            half8 hv = *(const half8*)xs;
#pragma unroll
            for (int i = 0; i < 8; i++) xacc[i] += nrm * (float)hv[i];
            nsum += nrm;
        } else {
            float xv[NL][8];
            float sc[NL];
#pragma unroll
            for (int t = 0; t < NL; t++) {
                half8 hv = *(const half8*)(xs + t * C);
#pragma unroll
                for (int i = 0; i < 8; i++) xv[t][i] = (float)hv[i];
                float part = z;
#pragma unroll
                for (int i = 0; i < 8; i++) part += xv[t][i] * y8[i];
                part += __shfl_xor(part, 4);   // combine the head's two groups
                sc[t] = part * scale;
            }
            float mx = sc[0];
#pragma unroll
            for (int t = 1; t < NL; t++) mx = fmaxf(mx, sc[t]);
            float s = 0.f;
            float ex[8] = {0.f, 0.f, 0.f, 0.f, 0.f, 0.f, 0.f, 0.f};
#pragma unroll
            for (int t = 0; t < NL; t++) {
                float e = __expf(sc[t] - mx);
                s += e;
#pragma unroll
                for (int i = 0; i < 8; i++) ex[i] += e * xv[t][i];
            }
            float inv = nrm * __builtin_amdgcn_rcpf(s);
#pragma unroll
            for (int i = 0; i < 8; i++) xacc[i] += inv * ex[i];
            nsum += nrm;
        }
    }

    // fold the 4 j4-slices of each group (lane bits 0,1)
#pragma unroll
    for (int i = 0; i < 8; i++) {
        xacc[i] += __shfl_xor(xacc[i], 1);
        xacc[i] += __shfl_xor(xacc[i], 2);
    }
    nsum += __shfl_xor(nsum, 1);
    nsum += __shfl_xor(nsum, 2);

    // epilogue: out[c0,c0+1] = relu(Wv xacc + bv*nsum)
    const float* wv = Wv + l * (G * CG * CG) + g * (CG * CG);
    float a0 = bv[l * C + c0] * nsum;
    float a1 = bv[l * C + c0 + 1] * nsum;
#pragma unroll
    for (int i = 0; i < 8; i++) {
        a0 += xacc[i] * wv[i * CG + o0];
        a1 += xacc[i] * wv[i * CG + o0 + 1];
    }
    a0 = fmaxf(a0, 0.f);
    a1 = fmaxf(a1, 0.f);
    float2 vo = make_float2(a0, a1);
    *(float2*)(x_all + (size_t)d * XSTRIDE + (l + 1) * C + c0) = vo;
    half2v ho;
    ho[0] = (_Float16)a0;
    ho[1] = (_Float16)a1;
    *(half2v*)(x16 + (size_t)d * X16STRIDE + (l + 1) * C + c0) = ho;
}

// ---- lin2: x_all[:,5,:] (n,128) @ w (128,16) + b -> out ----
__global__ __launch_bounds__(256) void k_lin2(const float* __restrict__ x_all,
                                              const float* __restrict__ w,
                                              const float* __restrict__ b,
                                              float* __restrict__ out) {
    __shared__ float sw[C * DIM_OUT];
    __shared__ float sb[DIM_OUT];
    __shared__ float sx[16][C];
    int tid = threadIdx.x;
    for (int i = tid; i < C * DIM_OUT; i += 256) sw[i] = w[i];
    if (tid < DIM_OUT) sb[tid] = b[tid];
    int node0 = blockIdx.x * 16;
    for (int i = tid; i < 16 * C; i += 256) {
        int nn = node0 + i / C;
        sx[i / C][i & (C - 1)] = (nn < N_NODES) ? x_all[(size_t)nn * XSTRIDE + 5 * C + (i & (C - 1))] : 0.0f;
    }
    __syncthreads();
    int node = node0 + tid / DIM_OUT;
    int o = tid & (DIM_OUT - 1);
    if (node >= N_NODES) return;
    float acc = sb[o];
    const float* xr = sx[tid / DIM_OUT];
#pragma unroll 8
    for (int c = 0; c < C; c++) acc += xr[c] * sw[c * DIM_OUT + o];
    out[node * DIM_OUT + o] = acc;
}

extern "C" void kernel_launch(void* const* d_in, const int* in_sizes, int n_in,
                              void* d_out, int out_size, void* d_ws, size_t ws_size,
                              hipStream_t stream) {
    const float* x      = (const float*)d_in[0];
    const int*   edge   = (const int*)d_in[1];
    const int*   row    = edge;              // edge_index[0]
    const int*   col    = edge + N_EDGESN;   // edge_index[1]
    const float* lin1_w = (const float*)d_in[2];
    const float* lin1_b = (const float*)d_in[3];
    const float* Wq     = (const float*)d_in[4];
    const float* bq     = (const float*)d_in[5];
    const float* Wk     = (const float*)d_in[6];
    const float* bk     = (const float*)d_in[7];
    const float* Wv     = (const float*)d_in[8];
    const float* bv     = (const float*)d_in[9];
    const float* lin2_w = (const float*)d_in[10];
    const float* lin2_b = (const float*)d_in[11];
    float* outp = (float*)d_out;

    float*     ws    = (float*)d_ws;
    float*     x_all = ws;                                             // n*6*C fp32
    _Float16*  x16   = (_Float16*)(x_all + (size_t)N_NODES * XSTRIDE); // n*6*C fp16
    float*     dis   = (float*)(x16 + (size_t)N_NODES * X16STRIDE);    // n
    int*   counts = (int*)(dis + N_NODES);                  // n
    int*   offs   = counts + N_NODES;                       // n+1
    int*   cursor = offs + N_NODES + 1;                     // n
    int2*  csr    = (int2*)(cursor + N_NODES);              // E_TOT int2

    k_zero<<<(N_NODES + 255) / 256, 256, 0, stream>>>(counts);
    k_count<<<(N_EDGESN + 255) / 256, 256, 0, stream>>>(col, counts);
    k_scan<<<1, 1024, 0, stream>>>(counts, offs, cursor, dis);
    k_scatter<<<(E_TOT + 255) / 256, 256, 0, stream>>>(row, col, dis, cursor, csr);
    k_lin1<<<N_NODES / 2, 256, 0, stream>>>(x, lin1_w, lin1_b, x_all, x16);

    const int ablocks = (N_NODES + 3) / 4;
    for (int l = 0; l < LLAYERS; l++) {
        switch (l) {
            case 0: k_attn_fly<1><<<ablocks, 256, 0, stream>>>(offs, csr, dis, Wq, bq, Wk, bk, Wv, bv, x_all, x16); break;
            case 1: k_attn_fly<2><<<ablocks, 256, 0, stream>>>(offs, csr, dis, Wq, bq, Wk, bk, Wv, bv, x_all, x16); break;
            case 2: k_attn_fly<3><<<ablocks, 256, 0, stream>>>(offs, csr, dis, Wq, bq, Wk, bk, Wv, bv, x_all, x16); break;
            case 3: k_attn_fly<4><<<ablocks, 256, 0, stream>>>(offs, csr, dis, Wq, bq, Wk, bk, Wv, bv, x_all, x16); break;
            case 4: k_attn_fly<5><<<ablocks, 256, 0, stream>>>(offs, csr, dis, Wq, bq, Wk, bk, Wv, bv, x_all, x16); break;
        }
    }
    k_lin2<<<(N_NODES + 15) / 16, 256, 0, stream>>>(x_all, lin2_w, lin2_b, outp);
}

// Round 10
// 231.398 us; speedup vs baseline: 2.2953x; 1.0329x over previous
//
#include <hip/hip_runtime.h>

#define N_NODES 10000
#define N_EDGESN 160000
#define E_TOT   (N_EDGESN + N_NODES)   // 170000
#define C 128
#define H 8
#define G 16
#define LLAYERS 5
#define NUM_FEAT 14
#define DIM_OUT 16
#define CH 16   // C/H
#define CG 8    // C/G
#define XSTRIDE (6*C)        // x_all row stride (6 layer slots), fp32
#define X16STRIDE (6*C)      // x16 row stride, fp16

typedef _Float16 half8 __attribute__((ext_vector_type(8)));
typedef _Float16 half2v __attribute__((ext_vector_type(2)));

// ---- counts = 1 (self loop) ----
__global__ void k_zero(int* __restrict__ counts) {
    int i = blockIdx.x * blockDim.x + threadIdx.x;
    if (i < N_NODES) counts[i] = 1;
}

// ---- degree count over original edges (by col) ----
__global__ void k_count(const int* __restrict__ col, int* __restrict__ counts) {
    int e = blockIdx.x * blockDim.x + threadIdx.x;
    if (e < N_EDGESN) atomicAdd(&counts[col[e]], 1);
}

// ---- single-block scan: counts -> exclusive offsets + cursor; dis = rsqrt(counts) ----
__global__ __launch_bounds__(1024) void k_scan(const int* __restrict__ counts,
                                               int* __restrict__ offs, int* __restrict__ cursor,
                                               float* __restrict__ dis) {
    __shared__ int part[1024];
    const int CHK = (N_NODES + 1023) / 1024;   // 10
    int t = threadIdx.x;
    int base = t * CHK;
    int loc[CHK];
    int sum = 0;
#pragma unroll
    for (int i = 0; i < CHK; i++) {
        int idx = base + i;
        int v = (idx < N_NODES) ? counts[idx] : 0;
        loc[i] = sum;
        sum += v;
    }
    part[t] = sum;
    __syncthreads();
    for (int off = 1; off < 1024; off <<= 1) {
        int v = (t >= off) ? part[t - off] : 0;
        __syncthreads();
        part[t] += v;
        __syncthreads();
    }
    int prev = (t > 0) ? part[t - 1] : 0;
#pragma unroll
    for (int i = 0; i < CHK; i++) {
        int idx = base + i;
        if (idx < N_NODES) {
            int o = prev + loc[i];
            offs[idx] = o;
            cursor[idx] = o;
            dis[idx] = rsqrtf((float)counts[idx]);
        }
    }
    if (t == 1023) offs[N_NODES] = part[1023];
}

// ---- scatter edges into dest-sorted CSR; payload = {src, dis[src]} ----
__global__ void k_scatter(const int* __restrict__ row, const int* __restrict__ col,
                          const float* __restrict__ dis,
                          int* __restrict__ cursor, int2* __restrict__ csr) {
    int e = blockIdx.x * blockDim.x + threadIdx.x;
    if (e >= E_TOT) return;
    int r = (e < N_EDGESN) ? row[e] : (e - N_EDGESN);
    int c = (e < N_EDGESN) ? col[e] : (e - N_EDGESN);
    int pos = atomicAdd(&cursor[c], 1);
    int2 pay;
    pay.x = r;
    pay.y = __float_as_int(dis[r]);
    csr[pos] = pay;
}

// ---- lin1: x (n,14) @ w (14,128) + b, relu -> x_all[:,0,:] (+ fp16 copy) ----
__global__ __launch_bounds__(256) void k_lin1(const float* __restrict__ x,
                                              const float* __restrict__ w,
                                              const float* __restrict__ b,
                                              float* __restrict__ x_all,
                                              _Float16* __restrict__ x16) {
    __shared__ float sw[NUM_FEAT * C];
    __shared__ float sb[C];
    int tid = threadIdx.x;
    for (int i = tid; i < NUM_FEAT * C; i += 256) sw[i] = w[i];
    if (tid < C) sb[tid] = b[tid];
    __syncthreads();
    int node = blockIdx.x * 2 + tid / C;
    int c = tid & (C - 1);
    if (node >= N_NODES) return;
    const float* xr = x + node * NUM_FEAT;
    float acc = sb[c];
#pragma unroll
    for (int f = 0; f < NUM_FEAT; f++) acc += xr[f] * sw[f * C + c];
    acc = fmaxf(acc, 0.0f);
    x_all[node * XSTRIDE + c] = acc;
    x16[(size_t)node * X16STRIDE + c] = (_Float16)acc;
}

__device__ __forceinline__ float dot8v(const float4& a, const float4& b,
                                       const float4& wa, const float4& wb) {
    return a.x * wa.x + a.y * wa.y + a.z * wa.z + a.w * wa.w
         + b.x * wb.x + b.y * wb.y + b.z * wb.z + b.w * wb.w;
}

// ---- fused attention layer: ONE WAVE PER NODE, fp16 gather, V-fold,
//      2-deep software pipeline (x of edge i+1 and payload of edge i+2
//      in flight while consuming edge i) ----
template <int NL>
__global__ __launch_bounds__(256) void k_attn_fly(const int* __restrict__ offs,
                                                  const int2* __restrict__ csr,
                                                  const float* __restrict__ dis,
                                                  const float* __restrict__ Wq, const float* __restrict__ bq,
                                                  const float* __restrict__ Wk, const float* __restrict__ bk,
                                                  const float* __restrict__ Wv, const float* __restrict__ bv,
                                                  float* __restrict__ x_all,
                                                  _Float16* __restrict__ x16) {
    const int l = NL - 1;
    int w = threadIdx.x >> 6;
    int lane = threadIdx.x & 63;
    int d = blockIdx.x * 4 + w;
    if (d >= N_NODES) return;
    int g = lane >> 2;       // channel group 0..15
    int j4 = lane & 3;       // edge slice within wave
    int c0 = 2 * lane;       // output channels c0, c0+1  (= 8g + 2*j4)
    int o0 = 2 * j4;

    float y8[8];
    float z = 0.f;
    if constexpr (NL > 1) {
        // ---- per-node precompute: q8 -> y8, z (fp32 path) ----
        const float* xq = x_all + (size_t)d * XSTRIDE + l * C + 8 * g;
        float4 xda = *(const float4*)xq;
        float4 xdb = *(const float4*)(xq + 4);
        const float* bqg = bq + l * C + 8 * g;
        float4 qa = *(const float4*)bqg;
        float4 qb = *(const float4*)(bqg + 4);
        const float* wq = Wq + l * (G * CG * CG) + g * (CG * CG);
        float xdv[8] = {xda.x, xda.y, xda.z, xda.w, xdb.x, xdb.y, xdb.z, xdb.w};
#pragma unroll
        for (int i = 0; i < 8; i++) {
            float4 ra = *(const float4*)(wq + i * CG);
            float4 rb = *(const float4*)(wq + i * CG + 4);
            qa.x += xdv[i] * ra.x; qa.y += xdv[i] * ra.y;
            qa.z += xdv[i] * ra.z; qa.w += xdv[i] * ra.w;
            qb.x += xdv[i] * rb.x; qb.y += xdv[i] * rb.y;
            qb.z += xdv[i] * rb.z; qb.w += xdv[i] * rb.w;
        }
        const float* wk = Wk + l * (G * CG * CG) + g * (CG * CG);
#pragma unroll
        for (int j = 0; j < 8; j++) {
            float4 ra = *(const float4*)(wk + j * CG);
            float4 rb = *(const float4*)(wk + j * CG + 4);
            y8[j] = dot8v(qa, qb, ra, rb);
        }
        const float* bkg = bk + l * C + 8 * g;
        z = dot8v(qa, qb, *(const float4*)bkg, *(const float4*)(bkg + 4));
    }

    const float disd = dis[d];
    const int p0 = offs[d], p1 = offs[d + 1];
    const float scale = 0.25f;   // 1/sqrt(CH=16)
    float xacc[8] = {0.f, 0.f, 0.f, 0.f, 0.f, 0.f, 0.f, 0.f};
    float nsum = 0.f;

    if constexpr (NL == 1) {
        for (int p = p0 + j4; p < p1; p += 4) {
            int2 pay = csr[p];
            float nrm = disd * __int_as_float(pay.y);
            const _Float16* xs = x16 + (size_t)pay.x * X16STRIDE + 8 * g;
            half8 hv = *(const half8*)xs;
#pragma unroll
            for (int i = 0; i < 8; i++) xacc[i] += nrm * (float)hv[i];
            nsum += nrm;
        }
    } else {
        // consume one edge (payload + preloaded fp16 x rows)
        auto consume = [&](int2 pay, const half8 (&buf)[NL]) {
            float nrm = disd * __int_as_float(pay.y);
            float xv[NL][8];
            float sc[NL];
#pragma unroll
            for (int t = 0; t < NL; t++) {
#pragma unroll
                for (int i = 0; i < 8; i++) xv[t][i] = (float)buf[t][i];
                float part = z;
#pragma unroll
                for (int i = 0; i < 8; i++) part += xv[t][i] * y8[i];
                part += __shfl_xor(part, 4);   // combine the head's two groups
                sc[t] = part * scale;
            }
            float mx = sc[0];
#pragma unroll
            for (int t = 1; t < NL; t++) mx = fmaxf(mx, sc[t]);
            float s = 0.f;
            float ex[8] = {0.f, 0.f, 0.f, 0.f, 0.f, 0.f, 0.f, 0.f};
#pragma unroll
            for (int t = 0; t < NL; t++) {
                float e = __expf(sc[t] - mx);
                s += e;
#pragma unroll
                for (int i = 0; i < 8; i++) ex[i] += e * xv[t][i];
            }
            float inv = nrm * __builtin_amdgcn_rcpf(s);
#pragma unroll
            for (int i = 0; i < 8; i++) xacc[i] += inv * ex[i];
            nsum += nrm;
        };

        int p = p0 + j4;
        if (p < p1) {
            int2 payA = csr[p];
            half8 bufA[NL];
            {
                const _Float16* xs = x16 + (size_t)payA.x * X16STRIDE + 8 * g;
#pragma unroll
                for (int t = 0; t < NL; t++) bufA[t] = *(const half8*)(xs + t * C);
            }
            int pn = p + 4;
            int2 payB = csr[(pn < p1) ? pn : p];   // safe prefetch
            for (; pn < p1; pn += 4) {
                // issue next edge's x loads (payB already resident)
                half8 bufB[NL];
                const _Float16* xs = x16 + (size_t)payB.x * X16STRIDE + 8 * g;
#pragma unroll
                for (int t = 0; t < NL; t++) bufB[t] = *(const half8*)(xs + t * C);
                // prefetch payload two ahead while consuming current edge
                int pc = pn + 4;
                int2 payC = csr[(pc < p1) ? pc : p0];
                consume(payA, bufA);
                payA = payB;
                payB = payC;
#pragma unroll
                for (int t = 0; t < NL; t++) bufA[t] = bufB[t];
            }
            consume(payA, bufA);
        }
    }

    // fold the 4 j4-slices of each group (lane bits 0,1)
#pragma unroll
    for (int i = 0; i < 8; i++) {
        xacc[i] += __shfl_xor(xacc[i], 1);
        xacc[i] += __shfl_xor(xacc[i], 2);
    }
    nsum += __shfl_xor(nsum, 1);
    nsum += __shfl_xor(nsum, 2);

    // epilogue: out[c0,c0+1] = relu(Wv xacc + bv*nsum)
    const float* wv = Wv + l * (G * CG * CG) + g * (CG * CG);
    float a0 = bv[l * C + c0] * nsum;
    float a1 = bv[l * C + c0 + 1] * nsum;
#pragma unroll
    for (int i = 0; i < 8; i++) {
        a0 += xacc[i] * wv[i * CG + o0];
        a1 += xacc[i] * wv[i * CG + o0 + 1];
    }
    a0 = fmaxf(a0, 0.f);
    a1 = fmaxf(a1, 0.f);
    float2 vo = make_float2(a0, a1);
    *(float2*)(x_all + (size_t)d * XSTRIDE + (l + 1) * C + c0) = vo;
    half2v ho;
    ho[0] = (_Float16)a0;
    ho[1] = (_Float16)a1;
    *(half2v*)(x16 + (size_t)d * X16STRIDE + (l + 1) * C + c0) = ho;
}

// ---- lin2: x_all[:,5,:] (n,128) @ w (128,16) + b -> out ----
__global__ __launch_bounds__(256) void k_lin2(const float* __restrict__ x_all,
                                              const float* __restrict__ w,
                                              const float* __restrict__ b,
                                              float* __restrict__ out) {
    __shared__ float sw[C * DIM_OUT];
    __shared__ float sb[DIM_OUT];
    __shared__ float sx[16][C];
    int tid = threadIdx.x;
    for (int i = tid; i < C * DIM_OUT; i += 256) sw[i] = w[i];
    if (tid < DIM_OUT) sb[tid] = b[tid];
    int node0 = blockIdx.x * 16;
    for (int i = tid; i < 16 * C; i += 256) {
        int nn = node0 + i / C;
        sx[i / C][i & (C - 1)] = (nn < N_NODES) ? x_all[(size_t)nn * XSTRIDE + 5 * C + (i & (C - 1))] : 0.0f;
    }
    __syncthreads();
    int node = node0 + tid / DIM_OUT;
    int o = tid & (DIM_OUT - 1);
    if (node >= N_NODES) return;
    float acc = sb[o];
    const float* xr = sx[tid / DIM_OUT];
#pragma unroll 8
    for (int c = 0; c < C; c++) acc += xr[c] * sw[c * DIM_OUT + o];
    out[node * DIM_OUT + o] = acc;
}

extern "C" void kernel_launch(void* const* d_in, const int* in_sizes, int n_in,
                              void* d_out, int out_size, void* d_ws, size_t ws_size,
                              hipStream_t stream) {
    const float* x      = (const float*)d_in[0];
    const int*   edge   = (const int*)d_in[1];
    const int*   row    = edge;              // edge_index[0]
    const int*   col    = edge + N_EDGESN;   // edge_index[1]
    const float* lin1_w = (const float*)d_in[2];
    const float* lin1_b = (const float*)d_in[3];
    const float* Wq     = (const float*)d_in[4];
    const float* bq     = (const float*)d_in[5];
    const float* Wk     = (const float*)d_in[6];
    const float* bk     = (const float*)d_in[7];
    const float* Wv     = (const float*)d_in[8];
    const float* bv     = (const float*)d_in[9];
    const float* lin2_w = (const float*)d_in[10];
    const float* lin2_b = (const float*)d_in[11];
    float* outp = (float*)d_out;

    float*     ws    = (float*)d_ws;
    float*     x_all = ws;                                             // n*6*C fp32
    _Float16*  x16   = (_Float16*)(x_all + (size_t)N_NODES * XSTRIDE); // n*6*C fp16
    float*     dis   = (float*)(x16 + (size_t)N_NODES * X16STRIDE);    // n
    int*   counts = (int*)(dis + N_NODES);                  // n
    int*   offs   = counts + N_NODES;                       // n+1
    int*   cursor = offs + N_NODES + 1;                     // n
    int2*  csr    = (int2*)(cursor + N_NODES);              // E_TOT int2

    k_zero<<<(N_NODES + 255) / 256, 256, 0, stream>>>(counts);
    k_count<<<(N_EDGESN + 255) / 256, 256, 0, stream>>>(col, counts);
    k_scan<<<1, 1024, 0, stream>>>(counts, offs, cursor, dis);
    k_scatter<<<(E_TOT + 255) / 256, 256, 0, stream>>>(row, col, dis, cursor, csr);
    k_lin1<<<N_NODES / 2, 256, 0, stream>>>(x, lin1_w, lin1_b, x_all, x16);

    const int ablocks = (N_NODES + 3) / 4;
    for (int l = 0; l < LLAYERS; l++) {
        switch (l) {
            case 0: k_attn_fly<1><<<ablocks, 256, 0, stream>>>(offs, csr, dis, Wq, bq, Wk, bk, Wv, bv, x_all, x16); break;
            case 1: k_attn_fly<2><<<ablocks, 256, 0, stream>>>(offs, csr, dis, Wq, bq, Wk, bk, Wv, bv, x_all, x16); break;
            case 2: k_attn_fly<3><<<ablocks, 256, 0, stream>>>(offs, csr, dis, Wq, bq, Wk, bk, Wv, bv, x_all, x16); break;
            case 3: k_attn_fly<4><<<ablocks, 256, 0, stream>>>(offs, csr, dis, Wq, bq, Wk, bk, Wv, bv, x_all, x16); break;
            case 4: k_attn_fly<5><<<ablocks, 256, 0, stream>>>(offs, csr, dis, Wq, bq, Wk, bk, Wv, bv, x_all, x16); break;
        }
    }
    k_lin2<<<(N_NODES + 15) / 16, 256, 0, stream>>>(x_all, lin2_w, lin2_b, outp);
}